// Round 14
// baseline (513.697 us; speedup 1.0000x reference)
//
#include <hip/hip_runtime.h>
#include <hip/hip_bf16.h>

// Shapes
#define M_CELLS 4096
#define N_GENES 4000
#define KP      4032   // 63 * 64, zero-padded K
#define NKT     63     // K tiles of 64
#define N_OUT   12288  // 64 patches * 192 embed
#define EMB     192
#define NPATCH  64

#define BM 256
#define BN 256
#define BK 64
#define BTILE (BN * BK)   // 16384 elems per B K-tile

typedef __attribute__((ext_vector_type(8))) short bf16x8_t;
typedef __attribute__((ext_vector_type(8))) unsigned short u16x8_t;
typedef __attribute__((ext_vector_type(4))) float f32x4_t;

__device__ __forceinline__ unsigned short f2bf(float f) {
  __hip_bfloat16 h = __float2bfloat16(f);
  return *reinterpret_cast<unsigned short*>(&h);
}

__device__ __forceinline__ void gll16(const unsigned short* g, unsigned short* l) {
  __builtin_amdgcn_global_load_lds(
      (const __attribute__((address_space(1))) void*)g,
      (__attribute__((address_space(3))) void*)l, 16, 0, 0);
}

// ---------------- fused prep ----------------------------------------------------------------
// Blocks [0,1008): prepA-v2 -> A2 FRAGMENT-LINEAR: A2[(mt*63+kt)*16384 + (wm*2+ks)*4096
//   + m*512 + lane*8 + e] = x[mt*256+wm*128+m*16+(lane&15)][kt*64+ks*32+(lane>>4)*8+e] (bf16,
//   zero-pad k>=4000). Each GEMM A-frag load = wave-uniform contiguous 1KB. Writes coalesced.
// Blocks [1008,4032): prepB (UNCHANGED layout Bt[nt][kt][c=256][k=64] for the LDS B-path).
__global__ __launch_bounds__(256) void prep_fused(const float* __restrict__ x,
                                                  const float* __restrict__ mask,
                                                  const float* __restrict__ W,
                                                  unsigned short* __restrict__ A2,
                                                  unsigned short* __restrict__ Bt) {
  __shared__ unsigned short sT[256 * 72];
  __shared__ float smask[256];
  const int t = threadIdx.x;
  if (blockIdx.x < 1008) {
    const int b  = blockIdx.x;
    const int mt = b / 63;
    const int kt = b - mt * 63;
    const size_t base = (size_t)(mt * NKT + kt) << 14;  // *16384 elems
#pragma unroll
    for (int it = 0; it < 8; ++it) {
      const int c    = it * 256 + t;       // 0..2047 (16B chunk index)
      const int lane = c & 63;
      const int fb5  = c >> 6;             // 0..31 : (wm,ks,m)
      const int wm   = fb5 >> 4, ks = (fb5 >> 3) & 1, mm = fb5 & 7;
      const int lr   = lane & 15, hi = lane >> 4;
      const int row  = (mt << 8) + (wm << 7) + (mm << 4) + lr;
      const int kg   = kt * 64 + ks * 32 + hi * 8;
      u16x8_t v;
      if (kg < N_GENES) {
        float4 f0 = *reinterpret_cast<const float4*>(x + (size_t)row * N_GENES + kg);
        float4 f1 = *reinterpret_cast<const float4*>(x + (size_t)row * N_GENES + kg + 4);
        v[0] = f2bf(f0.x); v[1] = f2bf(f0.y); v[2] = f2bf(f0.z); v[3] = f2bf(f0.w);
        v[4] = f2bf(f1.x); v[5] = f2bf(f1.y); v[6] = f2bf(f1.z); v[7] = f2bf(f1.w);
      } else {
        v = (u16x8_t)0;
      }
      *reinterpret_cast<u16x8_t*>(A2 + base + (size_t)c * 8) = v;
    }
  } else {
    const int idx = blockIdx.x - 1008;
    const int jb  = idx % 48;
    const int kt  = idx / 48;
    const int q   = t & 63;
    const int o   = t >> 6;
    const int pwbase = (jb * 256) / EMB;
    {
      const int kg_l = t & 63;
      const int pwi  = t >> 6;
      const int kg   = kt * 64 + kg_l;
      const int pw   = pwbase + pwi;
      float mv = 0.f;
      if (kg < N_GENES && pw < NPATCH) mv = mask[kg * NPATCH + pw];
      smask[kg_l * 4 + pwi] = mv;
    }
    __syncthreads();
    const int jbase = jb * 256 + q * 4;
    int pwi_[4];
#pragma unroll
    for (int dj = 0; dj < 4; ++dj) pwi_[dj] = (jbase + dj) / EMB - pwbase;

    u16x8_t hreg[4][2];
#pragma unroll
    for (int hb = 0; hb < 2; ++hb) {
#pragma unroll
      for (int kk8 = 0; kk8 < 8; ++kk8) {
        const int kk = hb * 8 + kk8;
        const int kg = kt * 64 + o * 16 + kk;
        float4 f;
        if (kg < N_GENES) f = *reinterpret_cast<const float4*>(W + (size_t)kg * N_OUT + jbase);
        else              f = make_float4(0.f, 0.f, 0.f, 0.f);
        const float fv[4] = {f.x, f.y, f.z, f.w};
#pragma unroll
        for (int dj = 0; dj < 4; ++dj) {
          float m = smask[(o * 16 + kk) * 4 + pwi_[dj]];
          hreg[dj][hb][kk8] = f2bf(fv[dj] * m);
        }
      }
    }
#pragma unroll
    for (int dj = 0; dj < 4; ++dj) {
      const int jl = q * 4 + dj;
#pragma unroll
      for (int hb = 0; hb < 2; ++hb) {
        const int s = (o * 2 + hb) ^ ((jl >> 2) & 7) ^ ((jl >> 5) & 7);
        *reinterpret_cast<u16x8_t*>(&sT[jl * 72 + s * 8]) = hreg[dj][hb];
      }
    }
    __syncthreads();
#pragma unroll
    for (int it = 0; it < 8; ++it) {
      const int f  = it * 256 + t;
      const int p  = f >> 5, u = f & 31;
      const int el = u >> 3;
      const int r  = el * 64 + p;
      const int s  = (u & 7) ^ ((r >> 2) & 7) ^ ((r >> 5) & 7);
      u16x8_t v = *reinterpret_cast<const u16x8_t*>(&sT[r * 72 + s * 8]);
      const int jp0 = p * EMB + jb * 4;
      const int nt  = jp0 >> 8, c = jp0 & 255;
      *reinterpret_cast<u16x8_t*>(&Bt[(size_t)(nt * NKT + kt) * BTILE + (size_t)c * 64 + u * 8]) = v;
    }
  }
}

// ---------------- main GEMM: 256x256, BK=64, B-in-LDS (R8 ring) + A DIRECT from L2 -----------
// LDS halves to 64 KB (B slots only). A-frags load straight from fragment-linear A2 via
// coalesced global_load_dwordx4, ping-ponged one region ahead (afX/afY) so the vmem drain
// rides under the MFMA bursts. Per-region vmem = 2 gll16 (B) + 8 A-loads; VMBAR(12) at each
// close forces region R-1's gll16 (slot first-read is 3 regions after stage -> safe) while
// leaving the current region's loads in flight. B reads/swizzle/stage identical to R8.
#define BBASE(buf, ks) (((buf) * 2 + (ks)) * 8192)

__global__ __launch_bounds__(512, 2) void gemm_bf16(const unsigned short* __restrict__ A2,
                                                    const unsigned short* __restrict__ Bt,
                                                    const float* __restrict__ bias,
                                                    float* __restrict__ out) {
  __shared__ unsigned short lds[32768];  // 64 KiB: 4 B-slots

  const int tid  = threadIdx.x;
  const int lane = tid & 63;
  const int wid  = tid >> 6;
  const int wm   = wid >> 2;   // 0..1
  const int wn   = wid & 3;    // 0..3
  const int lr   = lane & 15;
  const int hi   = lane >> 4;  // 0..3
  const int swz  = (lr >> 1) & 3;

  // XCD-chunked mapping: grid 768 = 8 XCDs x (16 mt x 6 nt_local).
  const int bid = blockIdx.x;
  const int xcd = bid & 7;
  const int l   = bid >> 3;
  const int mt  = l & 15;
  const int nt  = xcd * 6 + (l >> 4);
  const int m0  = mt * BM;
  const int n0  = nt * BN;

  // A direct-load base: frag (wm,ks,m) at kt -> aW + kt*16384 + ks*4096 + m*512
  const unsigned short* aW = A2 + (size_t)mt * NKT * 16384 + wm * 8192 + lane * 8;

  // B fragment LDS offsets (within a [256][32] chunk), swizzle slot^((row>>1)&3)
  const int boff = (wn * 64 + lr) * 32 + ((hi ^ swz) << 3);

  // B staging source (per-thread); LDS dest linear tid*16B
  const int srow = tid >> 2;
  const int ssl  = ((tid & 3) ^ ((tid >> 3) & 3)) << 3;
  const unsigned short* bS0 = Bt + (size_t)nt * NKT * BTILE + (size_t)srow * 64 + ssl;
  const unsigned short* bS1 = bS0 + 8192;

#define STAGE_B(kt, kh, buf) { \
    gll16(bS0 + (size_t)(kt) * BTILE + (kh) * 32, &lds[BBASE(buf, kh) + tid * 8]); \
    gll16(bS1 + (size_t)(kt) * BTILE + (kh) * 32, &lds[BBASE(buf, kh) + 4096 + tid * 8]); }

#define LOAD_A(REG, kt_, ks_) { \
    const unsigned short* ap_ = aW + ((size_t)(kt_) << 14) + ((ks_) << 12); \
    _Pragma("unroll") for (int m_ = 0; m_ < 8; ++m_) \
      REG[m_] = *reinterpret_cast<const bf16x8_t*>(ap_ + m_ * 512); }

#define RD_B4(buf, ks) \
    _Pragma("unroll") for (int n_ = 0; n_ < 4; ++n_) \
      bfr[n_] = *reinterpret_cast<const bf16x8_t*>(&lds[BBASE(buf, ks) + boff + n_ * 512]);

#define MM16A(AF) \
    __builtin_amdgcn_s_setprio(1); \
    _Pragma("unroll") for (int m_ = 0; m_ < 4; ++m_) \
    _Pragma("unroll") for (int n_ = 0; n_ < 4; ++n_) \
      acc[m_][n_] = __builtin_amdgcn_mfma_f32_16x16x32_bf16(AF[m_], bfr[n_], acc[m_][n_], 0, 0, 0); \
    __builtin_amdgcn_s_setprio(0);
#define MM16B(AF) \
    __builtin_amdgcn_s_setprio(1); \
    _Pragma("unroll") for (int m_ = 0; m_ < 4; ++m_) \
    _Pragma("unroll") for (int n_ = 0; n_ < 4; ++n_) \
      acc[4 + m_][n_] = __builtin_amdgcn_mfma_f32_16x16x32_bf16(AF[4 + m_], bfr[n_], acc[4 + m_][n_], 0, 0, 0); \
    __builtin_amdgcn_s_setprio(0);

#define VMBAR(N) \
    asm volatile("s_waitcnt vmcnt(" #N ")" ::: "memory"); \
    __builtin_amdgcn_s_barrier(); \
    asm volatile("" ::: "memory")

  f32x4_t acc[8][4] = {};
  bf16x8_t afX[8], afY[8], bfr[4];

  // Prologue: stage B for E0,E1,O0 (6 gll16); prime afX with chunk (0,k0).
  STAGE_B(0, 0, 0); STAGE_B(0, 1, 0); STAGE_B(1, 0, 1);
  LOAD_A(afX, 0, 0);
  VMBAR(8);   // forces the 6 gll16 (leaves the 8 A-loads in flight)

  for (int i = 0; i < 31; ++i) {
    const int ta = 2 * i, tb = 2 * i + 1, tc = 2 * i + 2;
    const int td = (tb + 2 <= 62) ? tb + 2 : 62;  // clamped dummy stage on last iter

    // R1: chunk (ta,k0), B slot E0; stage O1 <- B(tb,k1); prefetch A (ta,k1).
    STAGE_B(tb, 1, 1);
    LOAD_A(afY, ta, 1);
    RD_B4(0, 0);
    MM16A(afX); MM16B(afX);
    VMBAR(12);
    // R2: chunk (ta,k1), B slot E1; stage E0' <- B(tc,k0); prefetch A (tb,k0).
    STAGE_B(tc, 0, 0);
    LOAD_A(afX, tb, 0);
    RD_B4(0, 1);
    MM16A(afY); MM16B(afY);
    VMBAR(12);
    // R3: chunk (tb,k0), B slot O0; stage E1' <- B(tc,k1); prefetch A (tb,k1).
    STAGE_B(tc, 1, 0);
    LOAD_A(afY, tb, 1);
    RD_B4(1, 0);
    MM16A(afX); MM16B(afX);
    VMBAR(12);
    // R4: chunk (tb,k1), B slot O1; stage O0' <- B(td,k0); prefetch A (tc,k0).
    STAGE_B(td, 0, 1);
    LOAD_A(afX, tc, 0);
    RD_B4(1, 1);
    MM16A(afY); MM16B(afY);
    VMBAR(12);
  }

  // Tail: tile 62. E0=(62,k0) staged i30-R2 (forced i30-R3), E1=(62,k1) staged i30-R3
  // (forced i30-R4); afX holds (62,k0) from i30-R4. No restaging -> no barriers needed.
  LOAD_A(afY, 62, 1);
  RD_B4(0, 0);
  MM16A(afX); MM16B(afX);
  RD_B4(0, 1);
  MM16A(afY); MM16B(afY);
  asm volatile("s_waitcnt vmcnt(0)" ::: "memory");  // drain dummy O0' stage

  // Epilogue: C/D layout col=lane&15, row=(lane>>4)*4+reg. out flat = cell*12288 + j'.
#pragma unroll
  for (int n = 0; n < 4; ++n) {
    int jc = n0 + wn * 64 + n * 16 + lr;
    float bv = bias[(jc % EMB) * NPATCH + (jc / EMB)];
#pragma unroll
    for (int m = 0; m < 8; ++m) {
      int row = m0 + wm * 128 + m * 16 + hi * 4;
      float* o = out + (size_t)row * N_OUT + jc;
#pragma unroll
      for (int r = 0; r < 4; ++r)
        o[(size_t)r * N_OUT] = acc[m][n][r] + bv;
    }
  }
}

// ---------------- fallback (ws too small): simple fp32 LDS-tiled GEMM, correct but slow ------
__global__ __launch_bounds__(256) void fallback_gemm(const float* __restrict__ x,
                                                     const float* __restrict__ mask,
                                                     const float* __restrict__ W,
                                                     const float* __restrict__ b,
                                                     float* __restrict__ out) {
  __shared__ float sX[64 * 33];
  __shared__ float sB2[32 * 65];
  const int t  = threadIdx.x;
  const int c0 = blockIdx.x * 64;
  const int j0 = blockIdx.y * 64;
  const int tr = t >> 4, tc = t & 15;
  float acc[4][4] = {};
  for (int k0 = 0; k0 < N_GENES; k0 += 32) {
    __syncthreads();
#pragma unroll
    for (int i = 0; i < 8; ++i) {
      int f = i * 256 + t;
      int row = f >> 5, kk = f & 31;
      sX[row * 33 + kk] = x[(size_t)(c0 + row) * N_GENES + k0 + kk];
    }
#pragma unroll
    for (int i = 0; i < 8; ++i) {
      int f = i * 256 + t;
      int kk = f >> 6, cl = f & 63;
      int jp = j0 + cl;
      int jorig = (jp % EMB) * NPATCH + jp / EMB;
      sB2[kk * 65 + cl] = W[(size_t)(k0 + kk) * N_OUT + jorig] * mask[(k0 + kk) * NPATCH + jorig / EMB];
    }
    __syncthreads();
#pragma unroll
    for (int kk = 0; kk < 32; ++kk) {
      float a[4], bb[4];
#pragma unroll
      for (int r = 0; r < 4; ++r) a[r] = sX[(tr * 4 + r) * 33 + kk];
#pragma unroll
      for (int c = 0; c < 4; ++c) bb[c] = sB2[kk * 65 + tc * 4 + c];
#pragma unroll
      for (int r = 0; r < 4; ++r)
#pragma unroll
        for (int c = 0; c < 4; ++c) acc[r][c] += a[r] * bb[c];
    }
  }
#pragma unroll
  for (int r = 0; r < 4; ++r)
#pragma unroll
    for (int c = 0; c < 4; ++c) {
      int jp = j0 + tc * 4 + c;
      int jorig = (jp % EMB) * NPATCH + jp / EMB;
      out[(size_t)(c0 + tr * 4 + r) * N_OUT + jp] = acc[r][c] + b[jorig];
    }
}

extern "C" void kernel_launch(void* const* d_in, const int* in_sizes, int n_in,
                              void* d_out, int out_size, void* d_ws, size_t ws_size,
                              hipStream_t stream) {
  const float* x    = (const float*)d_in[0];
  const float* mask = (const float*)d_in[1];
  const float* W    = (const float*)d_in[2];
  const float* b    = (const float*)d_in[3];
  float* out = (float*)d_out;

  const size_t needA = (size_t)M_CELLS * KP * sizeof(unsigned short);  // 33.0 MB
  const size_t needB = (size_t)N_OUT * KP * sizeof(unsigned short);    // 99.1 MB

  if (ws_size >= needA + needB) {
    unsigned short* A2 = (unsigned short*)d_ws;
    unsigned short* Bt = (unsigned short*)((char*)d_ws + needA);
    prep_fused<<<4032, 256, 0, stream>>>(x, mask, W, A2, Bt);
    gemm_bf16<<<768, 512, 0, stream>>>(A2, Bt, b, out);
  } else {
    fallback_gemm<<<dim3(64, 192), 256, 0, stream>>>(x, mask, W, b, out);
  }
}

// Round 15
// 421.887 us; speedup vs baseline: 1.2176x; 1.2176x over previous
//
#include <hip/hip_runtime.h>
#include <hip/hip_bf16.h>

// Shapes
#define M_CELLS 4096
#define N_GENES 4000
#define KP      4032   // 63 * 64, zero-padded K
#define NKT     63     // K tiles of 64
#define N_OUT   12288  // 64 patches * 192 embed
#define EMB     192
#define NPATCH  64

#define BM 256
#define BN 256
#define BK 64
#define BTILE (BN * BK)   // 16384 elems per B K-tile

typedef __attribute__((ext_vector_type(8))) short bf16x8_t;
typedef __attribute__((ext_vector_type(8))) unsigned short u16x8_t;
typedef __attribute__((ext_vector_type(4))) float f32x4_t;

__device__ __forceinline__ unsigned short f2bf(float f) {
  __hip_bfloat16 h = __float2bfloat16(f);
  return *reinterpret_cast<unsigned short*>(&h);
}

__device__ __forceinline__ void gll16(const unsigned short* g, unsigned short* l) {
  __builtin_amdgcn_global_load_lds(
      (const __attribute__((address_space(1))) void*)g,
      (__attribute__((address_space(3))) void*)l, 16, 0, 0);
}

// ---------------- fused prep: blocks [0,1024) do prepA, [1024,4048) do prepB ----------------
// prepB v8: W loaded as float4 (16/thread); mask staged in LDS; sT pitch 72 with slot-XOR.
// Measured ~70 us vs ~63 us traffic floor — at BW roofline.
__global__ __launch_bounds__(256) void prep_fused(const float* __restrict__ x,
                                                  const float* __restrict__ mask,
                                                  const float* __restrict__ W,
                                                  unsigned short* __restrict__ A,
                                                  unsigned short* __restrict__ Bt) {
  __shared__ unsigned short sT[256 * 72];
  __shared__ float smask[256];
  const int t = threadIdx.x;
  if (blockIdx.x < 1024) {
    const int NG = M_CELLS * (KP / 8);
    for (int g = blockIdx.x * 256 + t; g < NG; g += 1024 * 256) {
      int row = g / (KP / 8);
      int kc  = g - row * (KP / 8);
      int k   = kc * 8;
      u16x8_t v;
      if (k < N_GENES) {
        float4 f0 = *reinterpret_cast<const float4*>(x + (size_t)row * N_GENES + k);
        float4 f1 = *reinterpret_cast<const float4*>(x + (size_t)row * N_GENES + k + 4);
        v[0] = f2bf(f0.x); v[1] = f2bf(f0.y); v[2] = f2bf(f0.z); v[3] = f2bf(f0.w);
        v[4] = f2bf(f1.x); v[5] = f2bf(f1.y); v[6] = f2bf(f1.z); v[7] = f2bf(f1.w);
      } else {
        v = (u16x8_t)0;
      }
      *reinterpret_cast<u16x8_t*>(A + (size_t)row * KP + k) = v;
    }
  } else {
    const int idx = blockIdx.x - 1024;
    const int jb  = idx % 48;
    const int kt  = idx / 48;
    const int q   = t & 63;      // j-quad index
    const int o   = t >> 6;      // k-16 block (wave-uniform)
    const int pwbase = (jb * 256) / EMB;
    {
      const int kg_l = t & 63;
      const int pwi  = t >> 6;
      const int kg   = kt * 64 + kg_l;
      const int pw   = pwbase + pwi;
      float mv = 0.f;
      if (kg < N_GENES && pw < NPATCH) mv = mask[kg * NPATCH + pw];
      smask[kg_l * 4 + pwi] = mv;
    }
    __syncthreads();
    const int jbase = jb * 256 + q * 4;
    int pwi_[4];
#pragma unroll
    for (int dj = 0; dj < 4; ++dj) pwi_[dj] = (jbase + dj) / EMB - pwbase;

    u16x8_t hreg[4][2];
#pragma unroll
    for (int hb = 0; hb < 2; ++hb) {
#pragma unroll
      for (int kk8 = 0; kk8 < 8; ++kk8) {
        const int kk = hb * 8 + kk8;
        const int kg = kt * 64 + o * 16 + kk;
        float4 f;
        if (kg < N_GENES) f = *reinterpret_cast<const float4*>(W + (size_t)kg * N_OUT + jbase);
        else              f = make_float4(0.f, 0.f, 0.f, 0.f);
        const float fv[4] = {f.x, f.y, f.z, f.w};
#pragma unroll
        for (int dj = 0; dj < 4; ++dj) {
          float m = smask[(o * 16 + kk) * 4 + pwi_[dj]];
          hreg[dj][hb][kk8] = f2bf(fv[dj] * m);
        }
      }
    }
#pragma unroll
    for (int dj = 0; dj < 4; ++dj) {
      const int jl = q * 4 + dj;
#pragma unroll
      for (int hb = 0; hb < 2; ++hb) {
        const int s = (o * 2 + hb) ^ ((jl >> 2) & 7) ^ ((jl >> 5) & 7);
        *reinterpret_cast<u16x8_t*>(&sT[jl * 72 + s * 8]) = hreg[dj][hb];
      }
    }
    __syncthreads();
#pragma unroll
    for (int it = 0; it < 8; ++it) {
      const int f  = it * 256 + t;
      const int p  = f >> 5, u = f & 31;
      const int el = u >> 3;
      const int r  = el * 64 + p;
      const int s  = (u & 7) ^ ((r >> 2) & 7) ^ ((r >> 5) & 7);
      u16x8_t v = *reinterpret_cast<const u16x8_t*>(&sT[r * 72 + s * 8]);
      const int jp0 = p * EMB + jb * 4;
      const int nt  = jp0 >> 8, c = jp0 & 255;
      *reinterpret_cast<u16x8_t*>(&Bt[(size_t)(nt * NKT + kt) * BTILE + (size_t)c * 64 + u * 8]) = v;
    }
  }
}

// ---------------- main GEMM: 256x256, BK=64, 2-window regions, 16x16x32 MFMA (R13 base) -----
// Best measured structure: 357 us GEMM, 1147 TF, 0 bank conflicts. This round's single
// change vs R13: s_setprio wrappers REMOVED (T5 is null-to-negative on lockstep
// barrier-synced GEMM structures — m190: -14 TF @8k from having it).
// A-direct (R14) hit the L2 ceiling via 4x wave-redundant A reads; 32x32 (R9-R12) carries
// a structural 2-lanes/row conflict; finer/coarser barrier cadences (R5-R7) measured equal.
#define ABASE(buf, ks) (((buf) * 2 + (ks)) * 8192)
#define BBASE(buf, ks) (32768 + ((buf) * 2 + (ks)) * 8192)

__global__ __launch_bounds__(512, 2) void gemm_bf16(const unsigned short* __restrict__ A,
                                                    const unsigned short* __restrict__ Bt,
                                                    const float* __restrict__ bias,
                                                    float* __restrict__ out) {
  __shared__ unsigned short lds[65536];  // 128 KiB

  const int tid  = threadIdx.x;
  const int lane = tid & 63;
  const int wid  = tid >> 6;
  const int wm   = wid >> 2;   // 0..1
  const int wn   = wid & 3;    // 0..3
  const int lr   = lane & 15;
  const int hi   = lane >> 4;  // 0..3
  const int swz  = (lr >> 1) & 3;

  // XCD-chunked mapping: grid 768 = 8 XCDs x (16 mt x 6 nt_local); mt fastest keeps the
  // 2 MB B-panel L2-resident across each XCD's 16-block mt sweep.
  const int bid = blockIdx.x;
  const int xcd = bid & 7;
  const int l   = bid >> 3;
  const int mt  = l & 15;
  const int nt  = xcd * 6 + (l >> 4);
  const int m0  = mt * BM;
  const int n0  = nt * BN;

  // fragment LDS element offsets (within a [256][32] chunk), swizzle slot^((row>>1)&3)
  const int aoff = (wm * 128 + lr) * 32 + ((hi ^ swz) << 3);
  const int boff = (wn * 64 + lr) * 32 + ((hi ^ swz) << 3);

  // staging source base pointers (per-thread); LDS dest linear tid*16B
  const int srow = tid >> 2;
  const int ssl  = ((tid & 3) ^ ((tid >> 3) & 3)) << 3;  // inverse-swizzled 16B slot
  const unsigned short* aS0 = A + (size_t)(m0 + srow) * KP + ssl;
  const unsigned short* aS1 = aS0 + (size_t)128 * KP;
  const unsigned short* bS0 = Bt + (size_t)nt * NKT * BTILE + (size_t)srow * 64 + ssl;
  const unsigned short* bS1 = bS0 + 8192;

#define STAGE_A(kt, kh, buf) { \
    gll16(aS0 + (kt) * 64 + (kh) * 32, &lds[ABASE(buf, kh) + tid * 8]); \
    gll16(aS1 + (kt) * 64 + (kh) * 32, &lds[ABASE(buf, kh) + 4096 + tid * 8]); }
#define STAGE_B(kt, kh, buf) { \
    gll16(bS0 + (size_t)(kt) * BTILE + (kh) * 32, &lds[BBASE(buf, kh) + tid * 8]); \
    gll16(bS1 + (size_t)(kt) * BTILE + (kh) * 32, &lds[BBASE(buf, kh) + 4096 + tid * 8]); }

#define RD_PA(buf, ks) { \
    afA[0] = *reinterpret_cast<const bf16x8_t*>(&lds[ABASE(buf, ks) + aoff]); \
    _Pragma("unroll") for (int n_ = 0; n_ < 4; ++n_) \
      bfr[n_] = *reinterpret_cast<const bf16x8_t*>(&lds[BBASE(buf, ks) + boff + n_ * 512]); \
    _Pragma("unroll") for (int m_ = 1; m_ < 4; ++m_) \
      afA[m_] = *reinterpret_cast<const bf16x8_t*>(&lds[ABASE(buf, ks) + aoff + m_ * 512]); }
#define RD_PB(buf, ks) \
    _Pragma("unroll") for (int m_ = 0; m_ < 4; ++m_) \
      afB[m_] = *reinterpret_cast<const bf16x8_t*>(&lds[ABASE(buf, ks) + aoff + (4 + m_) * 512]);

#define MM16A() \
    _Pragma("unroll") for (int m_ = 0; m_ < 4; ++m_) \
    _Pragma("unroll") for (int n_ = 0; n_ < 4; ++n_) \
      acc[m_][n_] = __builtin_amdgcn_mfma_f32_16x16x32_bf16(afA[m_], bfr[n_], acc[m_][n_], 0, 0, 0);
#define MM16B() \
    _Pragma("unroll") for (int m_ = 0; m_ < 4; ++m_) \
    _Pragma("unroll") for (int n_ = 0; n_ < 4; ++n_) \
      acc[4 + m_][n_] = __builtin_amdgcn_mfma_f32_16x16x32_bf16(afB[m_], bfr[n_], acc[4 + m_][n_], 0, 0, 0);

#define VMBAR(N) \
    asm volatile("s_waitcnt vmcnt(" #N ")" ::: "memory"); \
    __builtin_amdgcn_s_barrier(); \
    asm volatile("" ::: "memory")

  f32x4_t acc[8][4] = {};
  bf16x8_t afA[4], afB[4], bfr[4];

  // Prologue: stage E0, E1, O0 (12 loads); vmcnt(8) -> E0 done.
  STAGE_A(0, 0, 0); STAGE_B(0, 0, 0);
  STAGE_A(0, 1, 0); STAGE_B(0, 1, 0);
  STAGE_A(1, 0, 1); STAGE_B(1, 0, 1);
  VMBAR(8);

  for (int i = 0; i < 31; ++i) {
    const int tb = 2 * i + 1, tc = 2 * i + 2;
    const int td = (tb + 2 <= 62) ? tb + 2 : 62;  // clamped dummy stage on last iter

    // R1: stage O1 <- (tb,k1); compute E0. Close forces E1 (prologue/R-2) done.
    STAGE_A(tb, 1, 1); STAGE_B(tb, 1, 1);
    RD_PA(0, 0); MM16A();
    RD_PB(0, 0); MM16B();
    VMBAR(8);
    // R2: stage E0' <- (tc,k0); compute E1. Close forces O0 done.
    STAGE_A(tc, 0, 0); STAGE_B(tc, 0, 0);
    RD_PA(0, 1); MM16A();
    RD_PB(0, 1); MM16B();
    VMBAR(8);
    // R3: stage E1' <- (tc,k1); compute O0. Close forces O1 done.
    STAGE_A(tc, 1, 0); STAGE_B(tc, 1, 0);
    RD_PA(1, 0); MM16A();
    RD_PB(1, 0); MM16B();
    VMBAR(8);
    // R4: stage O0' <- (td,k0); compute O1. Close forces E0' done.
    STAGE_A(td, 0, 1); STAGE_B(td, 0, 1);
    RD_PA(1, 1); MM16A();
    RD_PB(1, 1); MM16B();
    VMBAR(8);
  }

  // Tail: tile 62 in E slots (E0 <- i30/R2 [forced done], E1 <- i30/R3).
  RD_PA(0, 0); MM16A();
  RD_PB(0, 0); MM16B();
  VMBAR(4);                          // forces R3's 4 -> E1 ready
  RD_PA(0, 1); MM16A();
  RD_PB(0, 1); MM16B();
  asm volatile("s_waitcnt vmcnt(0)" ::: "memory");  // drain dummy td stages
  __builtin_amdgcn_s_barrier();

  // Epilogue: C/D layout col=lane&15, row=(lane>>4)*4+reg. out flat = cell*12288 + j'.
#pragma unroll
  for (int n = 0; n < 4; ++n) {
    int jc = n0 + wn * 64 + n * 16 + lr;
    float bv = bias[(jc % EMB) * NPATCH + (jc / EMB)];
#pragma unroll
    for (int m = 0; m < 8; ++m) {
      int row = m0 + wm * 128 + m * 16 + hi * 4;
      float* o = out + (size_t)row * N_OUT + jc;
#pragma unroll
      for (int r = 0; r < 4; ++r)
        o[(size_t)r * N_OUT] = acc[m][n][r] + bv;
    }
  }
}

// ---------------- fallback (ws too small): simple fp32 LDS-tiled GEMM, correct but slow ------
__global__ __launch_bounds__(256) void fallback_gemm(const float* __restrict__ x,
                                                     const float* __restrict__ mask,
                                                     const float* __restrict__ W,
                                                     const float* __restrict__ b,
                                                     float* __restrict__ out) {
  __shared__ float sX[64 * 33];
  __shared__ float sB2[32 * 65];
  const int t  = threadIdx.x;
  const int c0 = blockIdx.x * 64;
  const int j0 = blockIdx.y * 64;
  const int tr = t >> 4, tc = t & 15;
  float acc[4][4] = {};
  for (int k0 = 0; k0 < N_GENES; k0 += 32) {
    __syncthreads();
#pragma unroll
    for (int i = 0; i < 8; ++i) {
      int f = i * 256 + t;
      int row = f >> 5, kk = f & 31;
      sX[row * 33 + kk] = x[(size_t)(c0 + row) * N_GENES + k0 + kk];
    }
#pragma unroll
    for (int i = 0; i < 8; ++i) {
      int f = i * 256 + t;
      int kk = f >> 6, cl = f & 63;
      int jp = j0 + cl;
      int jorig = (jp % EMB) * NPATCH + jp / EMB;
      sB2[kk * 65 + cl] = W[(size_t)(k0 + kk) * N_OUT + jorig] * mask[(k0 + kk) * NPATCH + jorig / EMB];
    }
    __syncthreads();
#pragma unroll
    for (int kk = 0; kk < 32; ++kk) {
      float a[4], bb[4];
#pragma unroll
      for (int r = 0; r < 4; ++r) a[r] = sX[(tr * 4 + r) * 33 + kk];
#pragma unroll
      for (int c = 0; c < 4; ++c) bb[c] = sB2[kk * 65 + tc * 4 + c];
#pragma unroll
      for (int r = 0; r < 4; ++r)
#pragma unroll
        for (int c = 0; c < 4; ++c) acc[r][c] += a[r] * bb[c];
    }
  }
#pragma unroll
  for (int r = 0; r < 4; ++r)
#pragma unroll
    for (int c = 0; c < 4; ++c) {
      int jp = j0 + tc * 4 + c;
      int jorig = (jp % EMB) * NPATCH + jp / EMB;
      out[(size_t)(c0 + tr * 4 + r) * N_OUT + jp] = acc[r][c] + b[jorig];
    }
}

extern "C" void kernel_launch(void* const* d_in, const int* in_sizes, int n_in,
                              void* d_out, int out_size, void* d_ws, size_t ws_size,
                              hipStream_t stream) {
  const float* x    = (const float*)d_in[0];
  const float* mask = (const float*)d_in[1];
  const float* W    = (const float*)d_in[2];
  const float* b    = (const float*)d_in[3];
  float* out = (float*)d_out;

  const size_t needA = (size_t)M_CELLS * KP * sizeof(unsigned short);  // 33.0 MB
  const size_t needB = (size_t)N_OUT * KP * sizeof(unsigned short);    // 99.1 MB

  if (ws_size >= needA + needB) {
    unsigned short* Abf = (unsigned short*)d_ws;
    unsigned short* Bt  = (unsigned short*)((char*)d_ws + needA);
    prep_fused<<<4048, 256, 0, stream>>>(x, mask, W, Abf, Bt);
    gemm_bf16<<<768, 512, 0, stream>>>(Abf, Bt, b, out);
  } else {
    fallback_gemm<<<dim3(64, 192), 256, 0, stream>>>(x, mask, W, b, out);
  }
}